// Round 9
// baseline (257.783 us; speedup 1.0000x reference)
//
#include <hip/hip_runtime.h>
#include <stdint.h>

#define D_DIM 2048
#define OUT_DIM 2048
#define NTOK 16384
#define SCALING 1.0f
#define NT32 68   // 64 K-tiles (BK=32) of x@W^T + 4 LoRA-extension tiles

typedef unsigned short u16;
typedef __attribute__((ext_vector_type(8))) short s16x8;
typedef __attribute__((ext_vector_type(4))) float f32x4;

// ws layout (bytes)
#define WZ_OFF  0u           // W bf16 swizzled [2048 o][2048 d]
#define AZ_OFF  8388608u     // experts_A^T bf16 swizzled [128 er][2048 d]
#define BZ_OFF  8912896u     // experts_B^T bf16 swizzled [2048 o][128 er]
#define CZ_OFF  9437184u     // c bf16 swizzled [16384 t][128 er]
#define XB_OFF  14155776u    // x bf16 swizzled [16384][2048]
#define WS_BIG   81264640u

__device__ inline u16 f2bf(float f) {
  union { float f; uint32_t u; } v; v.f = f;
  uint32_t u = v.u;
  u += 0x7FFFu + ((u >> 16) & 1u);   // round-to-nearest-even
  return (u16)(u >> 16);
}

// 32-granule swizzle: within each 32-elem chunk, 8-elem granule s ^= (row>>1)&3
__device__ inline int swz32(int c, int row) {
  return (c & ~31) | (((((c >> 3) & 3) ^ ((row >> 1) & 3))) << 3) | (c & 7);
}

#define GLDS(gp, lp) __builtin_amdgcn_global_load_lds( \
    (const __attribute__((address_space(1))) void*)(gp), \
    (__attribute__((address_space(3))) void*)(lp), 16, 0, 0)

// -------------- prep: cast + pre-swizzle W / experts_A^T / experts_B^T --------
__global__ __launch_bounds__(256) void k_prep(const float* __restrict__ W,
                                              const float* __restrict__ A,
                                              const float* __restrict__ Bf,
                                              u16* __restrict__ Wz,
                                              u16* __restrict__ Az,
                                              u16* __restrict__ Bz) {
  int bid = blockIdx.x;
  if (bid < 4096) {                      // W: 2048x2048 f32 -> bf16 swizzled
    int idx = bid * 256 + threadIdx.x;
    int o  = idx >> 9;
    int k0 = (idx & 511) * 4;
    const float4 v = *(const float4*)&W[(size_t)o * D_DIM + k0];
    int dst = swz32(k0, o);
    uint32_t p0 = (uint32_t)f2bf(v.x) | ((uint32_t)f2bf(v.y) << 16);
    uint32_t p1 = (uint32_t)f2bf(v.z) | ((uint32_t)f2bf(v.w) << 16);
    *(uint2*)&Wz[(size_t)o * D_DIM + dst] = make_uint2(p0, p1);
    return;
  }
  if (bid < 5120) {                      // experts_A -> A^T swizzled
    int idx = (bid - 4096) * 256 + threadIdx.x;
    float v = A[idx];
    int r = idx & 15;
    int d = (idx >> 4) & 2047;
    int e = idx >> 15;
    int er = e * 16 + r;
    Az[(size_t)er * D_DIM + swz32(d, er)] = f2bf(v);
    return;
  }
  {                                      // experts_B -> B^T swizzled
    int idx = (bid - 5120) * 256 + threadIdx.x;
    float v = Bf[idx];
    int er = idx >> 11;
    int o  = idx & 2047;
    Bz[(size_t)o * 128 + swz32(er, o)] = f2bf(v);
  }
}

// ---- merged router+lora: stream x once -> xb cast + exact-f32 logits + lora --
__global__ __launch_bounds__(256) void k_router_lora(
    const float* __restrict__ x, const float* __restrict__ rw,
    const u16* __restrict__ Az, u16* __restrict__ xb, u16* __restrict__ Cz) {
  __shared__ u16 Axl[2][64 * 64];     // x chunk bf16 swizzled [64 tok][64 k]
  __shared__ u16 Bzl[2][128 * 64];    // Az chunk [128 er][64 k]
  __shared__ float w8s[64 * 8];
  int tid = threadIdx.x, lane = tid & 63, wid = tid >> 6;
  int t0 = blockIdx.x * 64;
  const int l15 = lane & 15;

  f32x4 acc[8];
#pragma unroll
  for (int n = 0; n < 8; ++n) acc[n] = (f32x4){0.f, 0.f, 0.f, 0.f};
  float lgp[4][8];
#pragma unroll
  for (int i = 0; i < 4; ++i)
#pragma unroll
    for (int e = 0; e < 8; ++e) lgp[i][e] = 0.f;

  auto stage = [&](int kc, int buf) {
    bool real = (kc <= 31);
    if (!real) kc = 31;
    const int c4 = (tid & 15) * 4;
    float4 rv[8];
    if (real) {
#pragma unroll
      for (int e = 0; e < 8; ++e)
        rv[e] = *(const float4*)&rw[(size_t)e * D_DIM + kc * 64 + c4];
    }
#pragma unroll
    for (int i = 0; i < 4; ++i) {
      int row = i * 16 + (tid >> 4);
      float4 v = *(const float4*)&x[(size_t)(t0 + row) * D_DIM + kc * 64 + c4];
      uint32_t p0 = (uint32_t)f2bf(v.x) | ((uint32_t)f2bf(v.y) << 16);
      uint32_t p1 = (uint32_t)f2bf(v.z) | ((uint32_t)f2bf(v.w) << 16);
      *(uint2*)&xb[(size_t)(t0 + row) * D_DIM + swz32(kc * 64 + c4, row)] =
          make_uint2(p0, p1);
      *(uint2*)&Axl[buf][row * 64 + swz32(c4, row)] = make_uint2(p0, p1);
      if (real) {
#pragma unroll
        for (int e = 0; e < 8; ++e) {
          lgp[i][e] = fmaf(v.x, rv[e].x, lgp[i][e]);
          lgp[i][e] = fmaf(v.y, rv[e].y, lgp[i][e]);
          lgp[i][e] = fmaf(v.z, rv[e].z, lgp[i][e]);
          lgp[i][e] = fmaf(v.w, rv[e].w, lgp[i][e]);
        }
      }
    }
#pragma unroll
    for (int i = 0; i < 4; ++i) {
      const u16* g = Az + (size_t)(i * 32 + (tid >> 3)) * D_DIM + kc * 64 + (tid & 7) * 8;
      GLDS(g, &Bzl[buf][0] + i * 2048 + tid * 8);
    }
  };

  stage(0, 0);
  asm volatile("s_waitcnt vmcnt(0) lgkmcnt(0)" ::: "memory");
  __builtin_amdgcn_s_barrier();

  for (int kc = 0; kc < 32; ++kc) {
    int cur = kc & 1;
    stage(kc + 1, cur ^ 1);
    const int g = (lane >> 4) ^ ((l15 >> 1) & 3);
#pragma unroll
    for (int kk = 0; kk < 2; ++kk) {
      s16x8 af = *(const s16x8*)&Axl[cur][(wid * 16 + l15) * 64 + kk * 32 + g * 8];
#pragma unroll
      for (int nf = 0; nf < 8; ++nf) {
        s16x8 bf = *(const s16x8*)&Bzl[cur][(nf * 16 + l15) * 64 + kk * 32 + g * 8];
        acc[nf] = __builtin_amdgcn_mfma_f32_16x16x32_bf16(af, bf, acc[nf], 0, 0, 0);
      }
    }
    asm volatile("s_waitcnt vmcnt(0) lgkmcnt(0)" ::: "memory");
    __builtin_amdgcn_s_barrier();
  }

  // reduce logit partials over the 16-lane c4 groups (exact f32)
#pragma unroll
  for (int i = 0; i < 4; ++i) {
#pragma unroll
    for (int e = 0; e < 8; ++e) {
      float v = lgp[i][e];
      v += __shfl_xor(v, 1, 64);
      v += __shfl_xor(v, 2, 64);
      v += __shfl_xor(v, 4, 64);
      v += __shfl_xor(v, 8, 64);
      lgp[i][e] = v;
    }
    // top-2 (strict >, lowest index wins ties, matching lax.top_k) + softmax
    float l0 = lgp[i][0]; int i0 = 0;
#pragma unroll
    for (int e = 1; e < 8; ++e) if (lgp[i][e] > l0) { l0 = lgp[i][e]; i0 = e; }
    float l1 = -3e38f; int i1 = 0;
#pragma unroll
    for (int e = 0; e < 8; ++e) if (e != i0 && lgp[i][e] > l1) { l1 = lgp[i][e]; i1 = e; }
    float e1 = expf(l1 - l0);
    float inv = 1.f / (1.f + e1);
    if (l15 < 8) {
      int row = i * 16 + (tid >> 4);
      w8s[row * 8 + l15] =
          (l15 == i0) ? inv * SCALING : (l15 == i1) ? e1 * inv * SCALING : 0.f;
    }
  }
  __syncthreads();

  // scale + write Cz (expert index == nf since er = nf*16 + l15, l15 < 16)
#pragma unroll
  for (int q = 0; q < 4; ++q) {
    int rl = wid * 16 + (lane >> 4) * 4 + q;
#pragma unroll
    for (int nf = 0; nf < 8; ++nf) {
      float v = acc[nf][q] * w8s[rl * 8 + nf];
      int er = nf * 16 + l15;
      Cz[(size_t)(t0 + rl) * 128 + swz32(er, rl)] = f2bf(v);
    }
  }
}

// ------ 128^2 main GEMM: BK=32, 2-buf, reg-dbuf, ~3 blocks/CU ------------------
__global__ __launch_bounds__(256, 3) void k_main128(const u16* __restrict__ xb,
                                                    const u16* __restrict__ Wz,
                                                    const u16* __restrict__ Cz,
                                                    const u16* __restrict__ Bz,
                                                    float* __restrict__ out) {
  __shared__ u16 AL[2][4096];   // [128 rows][32 cols] per buf
  __shared__ u16 BL[2][4096];
  const int tid = threadIdx.x, lane = tid & 63;
  const int wid = tid >> 6, wm = wid >> 1, wn = wid & 1;
  int bid = blockIdx.x;                     // 2048 blocks, %8 == 0
  int swz = (bid & 7) * 256 + (bid >> 3);   // XCD-aware, bijective
  int mt = swz >> 4, nt = swz & 15;
  int t0 = mt * 128, o0 = nt * 128;
  const int l15 = lane & 15;
  const int gA = (lane >> 4) ^ ((l15 >> 1) & 3);
  const int aoff = (wm * 64 + l15) * 32 + gA * 8;   // frag i at +i*512
  const int boff = (wn * 64 + l15) * 32 + gA * 8;
  const int srow = tid >> 2, sc8 = (tid & 3) * 8;

  f32x4 acc[4][4];
#pragma unroll
  for (int m = 0; m < 4; ++m)
#pragma unroll
    for (int n = 0; n < 4; ++n) acc[m][n] = (f32x4){0.f, 0.f, 0.f, 0.f};
  s16x8 aA[4], bA[4], aB[4], bB[4];

  auto stg = [&](int t, int bufi) {
    if (t > NT32 - 1) t = NT32 - 1;   // tail clamp: benign rewrite
    const u16 *sa, *sb; int lda, ldb, ca;
    if (t < 64) { sa = xb; lda = D_DIM; sb = Wz; ldb = D_DIM; ca = t * 32; }
    else        { sa = Cz; lda = 128;   sb = Bz; ldb = 128;   ca = (t - 64) * 32; }
#pragma unroll
    for (int i = 0; i < 2; ++i) {
      const u16* g = sa + (size_t)(t0 + i * 64 + srow) * lda + ca + sc8;
      GLDS(g, &AL[bufi][0] + i * 2048 + tid * 8);
      const u16* h = sb + (size_t)(o0 + i * 64 + srow) * ldb + ca + sc8;
      GLDS(h, &BL[bufi][0] + i * 2048 + tid * 8);
    }
  };

#define RD(av, bv, bufi) do {                                            \
    _Pragma("unroll") for (int i_ = 0; i_ < 4; ++i_)                     \
      av[i_] = *(const s16x8*)&AL[bufi][aoff + i_ * 512];                \
    _Pragma("unroll") for (int j_ = 0; j_ < 4; ++j_)                     \
      bv[j_] = *(const s16x8*)&BL[bufi][boff + j_ * 512];                \
  } while (0)

#define MM(av, bv) do {                                                  \
    _Pragma("unroll") for (int mf_ = 0; mf_ < 4; ++mf_)                  \
      _Pragma("unroll") for (int nf_ = 0; nf_ < 4; ++nf_)                \
        acc[mf_][nf_] = __builtin_amdgcn_mfma_f32_16x16x32_bf16(         \
            av[mf_], bv[nf_], acc[mf_][nf_], 0, 0, 0);                   \
  } while (0)

  // prologue
  stg(0, 0);
  asm volatile("s_waitcnt vmcnt(0)" ::: "memory");
  __builtin_amdgcn_s_barrier();
  RD(aA, bA, 0);
  stg(1, 1);
  asm volatile("s_waitcnt vmcnt(0) lgkmcnt(0)" ::: "memory");
  __builtin_amdgcn_s_barrier();

  for (int jj = 0; jj < NT32; jj += 2) {
    // I_jj: compute tile jj (regs aA/bA); buf0 freed (tile jj reg-read & drained)
    RD(aB, bB, 1);                 // tile jj+1 (published)
    stg(jj + 2, 0);
    MM(aA, bA);
    asm volatile("s_waitcnt vmcnt(0) lgkmcnt(0)" ::: "memory");
    __builtin_amdgcn_s_barrier();
    // I_{jj+1}: compute tile jj+1; buf1 freed
    RD(aA, bA, 0);                 // tile jj+2
    stg(jj + 3, 1);
    MM(aB, bB);
    asm volatile("s_waitcnt vmcnt(0) lgkmcnt(0)" ::: "memory");
    __builtin_amdgcn_s_barrier();
  }
#undef RD
#undef MM

#pragma unroll
  for (int mf = 0; mf < 4; ++mf)
#pragma unroll
    for (int q = 0; q < 4; ++q) {
      int row = t0 + wm * 64 + mf * 16 + (lane >> 4) * 4 + q;
#pragma unroll
      for (int nf = 0; nf < 4; ++nf) {
        int col = o0 + wn * 64 + nf * 16 + l15;
        out[(size_t)row * OUT_DIM + col] = acc[mf][nf][q];
      }
    }
}

extern "C" void kernel_launch(void* const* d_in, const int* in_sizes, int n_in,
                              void* d_out, int out_size, void* d_ws, size_t ws_size,
                              hipStream_t stream) {
  const float* x  = (const float*)d_in[0];
  const float* W  = (const float*)d_in[1];
  const float* rw = (const float*)d_in[2];
  const float* eA = (const float*)d_in[3];
  const float* eB = (const float*)d_in[4];
  float* out = (float*)d_out;
  char* ws = (char*)d_ws;
  if (ws_size < WS_BIG) return;

  u16* Wz = (u16*)(ws + WZ_OFF);
  u16* Az = (u16*)(ws + AZ_OFF);
  u16* Bz = (u16*)(ws + BZ_OFF);
  u16* Cz = (u16*)(ws + CZ_OFF);
  u16* xb = (u16*)(ws + XB_OFF);

  k_prep<<<6144, 256, 0, stream>>>(W, eA, eB, Wz, Az, Bz);
  k_router_lora<<<256, 256, 0, stream>>>(x, rw, Az, xb, Cz);
  k_main128<<<2048, 256, 0, stream>>>(xb, Wz, Cz, Bz, out);
}

// Round 10
// 225.455 us; speedup vs baseline: 1.1434x; 1.1434x over previous
//
#include <hip/hip_runtime.h>
#include <stdint.h>

#define D_DIM 2048
#define OUT_DIM 2048
#define NTOK 16384
#define SCALING 1.0f
#define NT32 68   // 64 K-tiles (BK=32) of x@W^T + 4 LoRA-extension tiles

typedef unsigned short u16;
typedef __attribute__((ext_vector_type(8))) short s16x8;
typedef __attribute__((ext_vector_type(4))) float f32x4;

// ws layout (bytes)
#define WZ_OFF  0u           // W bf16 swizzled [2048 o][2048 d]
#define AZ_OFF  8388608u     // experts_A^T bf16 swizzled [128 er][2048 d]
#define BZ_OFF  8912896u     // experts_B^T bf16 swizzled [2048 o][128 er]
#define CZ_OFF  9437184u     // c bf16 swizzled [16384 t][128 er]
#define XB_OFF  14155776u    // x bf16 swizzled [16384][2048]
#define WS_BIG   81264640u

__device__ inline u16 f2bf(float f) {
  union { float f; uint32_t u; } v; v.f = f;
  uint32_t u = v.u;
  u += 0x7FFFu + ((u >> 16) & 1u);   // round-to-nearest-even
  return (u16)(u >> 16);
}

// 32-granule swizzle: within each 32-elem chunk, 8-elem granule s ^= (row>>1)&3
__device__ inline int swz32(int c, int row) {
  return (c & ~31) | (((((c >> 3) & 3) ^ ((row >> 1) & 3))) << 3) | (c & 7);
}

#define GLDS(gp, lp) __builtin_amdgcn_global_load_lds( \
    (const __attribute__((address_space(1))) void*)(gp), \
    (__attribute__((address_space(3))) void*)(lp), 16, 0, 0)

// -------------- prep: cast + pre-swizzle W / experts_A^T / experts_B^T --------
__global__ __launch_bounds__(256) void k_prep(const float* __restrict__ W,
                                              const float* __restrict__ A,
                                              const float* __restrict__ Bf,
                                              u16* __restrict__ Wz,
                                              u16* __restrict__ Az,
                                              u16* __restrict__ Bz) {
  int bid = blockIdx.x;
  if (bid < 4096) {                      // W: 2048x2048 f32 -> bf16 swizzled
    int idx = bid * 256 + threadIdx.x;
    int o  = idx >> 9;
    int k0 = (idx & 511) * 4;
    const float4 v = *(const float4*)&W[(size_t)o * D_DIM + k0];
    int dst = swz32(k0, o);
    uint32_t p0 = (uint32_t)f2bf(v.x) | ((uint32_t)f2bf(v.y) << 16);
    uint32_t p1 = (uint32_t)f2bf(v.z) | ((uint32_t)f2bf(v.w) << 16);
    *(uint2*)&Wz[(size_t)o * D_DIM + dst] = make_uint2(p0, p1);
    return;
  }
  if (bid < 5120) {                      // experts_A -> A^T swizzled
    int idx = (bid - 4096) * 256 + threadIdx.x;
    float v = A[idx];
    int r = idx & 15;
    int d = (idx >> 4) & 2047;
    int e = idx >> 15;
    int er = e * 16 + r;
    Az[(size_t)er * D_DIM + swz32(d, er)] = f2bf(v);
    return;
  }
  {                                      // experts_B -> B^T swizzled
    int idx = (bid - 5120) * 256 + threadIdx.x;
    float v = Bf[idx];
    int er = idx >> 11;
    int o  = idx & 2047;
    Bz[(size_t)o * 128 + swz32(er, o)] = f2bf(v);
  }
}

// ---- merged router+lora: stream x once -> xb cast + exact-f32 logits + lora --
__global__ __launch_bounds__(256) void k_router_lora(
    const float* __restrict__ x, const float* __restrict__ rw,
    const u16* __restrict__ Az, u16* __restrict__ xb, u16* __restrict__ Cz) {
  __shared__ u16 Axl[2][64 * 64];     // x chunk bf16 swizzled [64 tok][64 k]
  __shared__ u16 Bzl[2][128 * 64];    // Az chunk [128 er][64 k]
  __shared__ float w8s[64 * 8];
  int tid = threadIdx.x, lane = tid & 63, wid = tid >> 6;
  int t0 = blockIdx.x * 64;
  const int l15 = lane & 15;

  f32x4 acc[8];
#pragma unroll
  for (int n = 0; n < 8; ++n) acc[n] = (f32x4){0.f, 0.f, 0.f, 0.f};
  float lgp[4][8];
#pragma unroll
  for (int i = 0; i < 4; ++i)
#pragma unroll
    for (int e = 0; e < 8; ++e) lgp[i][e] = 0.f;

  auto stage = [&](int kc, int buf) {
    bool real = (kc <= 31);
    if (!real) kc = 31;
    const int c4 = (tid & 15) * 4;
    float4 rv[8];
    if (real) {
#pragma unroll
      for (int e = 0; e < 8; ++e)
        rv[e] = *(const float4*)&rw[(size_t)e * D_DIM + kc * 64 + c4];
    }
#pragma unroll
    for (int i = 0; i < 4; ++i) {
      int row = i * 16 + (tid >> 4);
      float4 v = *(const float4*)&x[(size_t)(t0 + row) * D_DIM + kc * 64 + c4];
      uint32_t p0 = (uint32_t)f2bf(v.x) | ((uint32_t)f2bf(v.y) << 16);
      uint32_t p1 = (uint32_t)f2bf(v.z) | ((uint32_t)f2bf(v.w) << 16);
      *(uint2*)&xb[(size_t)(t0 + row) * D_DIM + swz32(kc * 64 + c4, row)] =
          make_uint2(p0, p1);
      *(uint2*)&Axl[buf][row * 64 + swz32(c4, row)] = make_uint2(p0, p1);
      if (real) {
#pragma unroll
        for (int e = 0; e < 8; ++e) {
          lgp[i][e] = fmaf(v.x, rv[e].x, lgp[i][e]);
          lgp[i][e] = fmaf(v.y, rv[e].y, lgp[i][e]);
          lgp[i][e] = fmaf(v.z, rv[e].z, lgp[i][e]);
          lgp[i][e] = fmaf(v.w, rv[e].w, lgp[i][e]);
        }
      }
    }
#pragma unroll
    for (int i = 0; i < 4; ++i) {
      const u16* g = Az + (size_t)(i * 32 + (tid >> 3)) * D_DIM + kc * 64 + (tid & 7) * 8;
      GLDS(g, &Bzl[buf][0] + i * 2048 + tid * 8);
    }
  };

  stage(0, 0);
  asm volatile("s_waitcnt vmcnt(0) lgkmcnt(0)" ::: "memory");
  __builtin_amdgcn_s_barrier();

  for (int kc = 0; kc < 32; ++kc) {
    int cur = kc & 1;
    stage(kc + 1, cur ^ 1);
    const int g = (lane >> 4) ^ ((l15 >> 1) & 3);
#pragma unroll
    for (int kk = 0; kk < 2; ++kk) {
      s16x8 af = *(const s16x8*)&Axl[cur][(wid * 16 + l15) * 64 + kk * 32 + g * 8];
#pragma unroll
      for (int nf = 0; nf < 8; ++nf) {
        s16x8 bf = *(const s16x8*)&Bzl[cur][(nf * 16 + l15) * 64 + kk * 32 + g * 8];
        acc[nf] = __builtin_amdgcn_mfma_f32_16x16x32_bf16(af, bf, acc[nf], 0, 0, 0);
      }
    }
    asm volatile("s_waitcnt vmcnt(0) lgkmcnt(0)" ::: "memory");
    __builtin_amdgcn_s_barrier();
  }

  // reduce logit partials over the 16-lane c4 groups (exact f32)
#pragma unroll
  for (int i = 0; i < 4; ++i) {
#pragma unroll
    for (int e = 0; e < 8; ++e) {
      float v = lgp[i][e];
      v += __shfl_xor(v, 1, 64);
      v += __shfl_xor(v, 2, 64);
      v += __shfl_xor(v, 4, 64);
      v += __shfl_xor(v, 8, 64);
      lgp[i][e] = v;
    }
    // top-2 (strict >, lowest index wins ties, matching lax.top_k) + softmax
    float l0 = lgp[i][0]; int i0 = 0;
#pragma unroll
    for (int e = 1; e < 8; ++e) if (lgp[i][e] > l0) { l0 = lgp[i][e]; i0 = e; }
    float l1 = -3e38f; int i1 = 0;
#pragma unroll
    for (int e = 0; e < 8; ++e) if (e != i0 && lgp[i][e] > l1) { l1 = lgp[i][e]; i1 = e; }
    float e1 = expf(l1 - l0);
    float inv = 1.f / (1.f + e1);
    if (l15 < 8) {
      int row = i * 16 + (tid >> 4);
      w8s[row * 8 + l15] =
          (l15 == i0) ? inv * SCALING : (l15 == i1) ? e1 * inv * SCALING : 0.f;
    }
  }
  __syncthreads();

  // scale + write Cz (expert index == nf since er = nf*16 + l15, l15 < 16)
#pragma unroll
  for (int q = 0; q < 4; ++q) {
    int rl = wid * 16 + (lane >> 4) * 4 + q;
#pragma unroll
    for (int nf = 0; nf < 8; ++nf) {
      float v = acc[nf][q] * w8s[rl * 8 + nf];
      int er = nf * 16 + l15;
      Cz[(size_t)(t0 + rl) * 128 + swz32(er, rl)] = f2bf(v);
    }
  }
}

// ------ 256^2 main GEMM: BK=32, 4-buffer rotation, counted vmcnt, setprio ------
__global__ __launch_bounds__(512, 2) void k_main32(const u16* __restrict__ xb,
                                                   const u16* __restrict__ Wz,
                                                   const u16* __restrict__ Cz,
                                                   const u16* __restrict__ Bz,
                                                   float* __restrict__ out) {
  __shared__ u16 AL[4][8192];   // 4 bufs x [256 rows][32 cols]
  __shared__ u16 BL[4][8192];
  const int tid = threadIdx.x, lane = tid & 63;
  const int wid = tid >> 6, wm = wid >> 2, wn = wid & 3;
  int bid = blockIdx.x;                     // 512 blocks, 512 % 8 == 0
  int swz = (bid & 7) * 64 + (bid >> 3);    // XCD-aware, bijective
  int mt = swz >> 3, nt = swz & 7;
  int t0 = mt * 256, o0 = nt * 256;
  const int l15 = lane & 15;
  const int gA = (lane >> 4) ^ ((l15 >> 1) & 3);
  const int aoff = (wm * 128 + l15) * 32 + gA * 8;   // frag i at +i*512
  const int boff = (wn * 64 + l15) * 32 + gA * 8;
  const int srow = tid >> 2, sc8 = (tid & 3) * 8;

  f32x4 acc[8][4];
#pragma unroll
  for (int m = 0; m < 8; ++m)
#pragma unroll
    for (int n = 0; n < 4; ++n) acc[m][n] = (f32x4){0.f, 0.f, 0.f, 0.f};
  s16x8 aA[8], bA[4], aB[8], bB[4];

  // stage tile t (clamped src) into buffer bufi: 2 A-loads + 2 B-loads
  auto stg = [&](int t, int bufi) {
    if (t > NT32 - 1) t = NT32 - 1;
    const u16 *sa, *sb; int lda, ldb, ca;
    if (t < 64) { sa = xb; lda = D_DIM; sb = Wz; ldb = D_DIM; ca = t * 32; }
    else        { sa = Cz; lda = 128;   sb = Bz; ldb = 128;   ca = (t - 64) * 32; }
#pragma unroll
    for (int i = 0; i < 2; ++i) {
      const u16* g = sa + (size_t)(t0 + i * 128 + srow) * lda + ca + sc8;
      GLDS(g, &AL[bufi][0] + i * 4096 + tid * 8);
    }
#pragma unroll
    for (int i = 0; i < 2; ++i) {
      const u16* g = sb + (size_t)(o0 + i * 128 + srow) * ldb + ca + sc8;
      GLDS(g, &BL[bufi][0] + i * 4096 + tid * 8);
    }
  };

#define RD(av, bv, bufi) do {                                           \
    const u16* ap_ = &AL[bufi][aoff];                                   \
    const u16* bp_ = &BL[bufi][boff];                                   \
    _Pragma("unroll") for (int i_ = 0; i_ < 8; ++i_)                    \
      av[i_] = *(const s16x8*)(ap_ + i_ * 512);                         \
    _Pragma("unroll") for (int j_ = 0; j_ < 4; ++j_)                    \
      bv[j_] = *(const s16x8*)(bp_ + j_ * 512);                         \
  } while (0)

#define MM(av, bv) do {                                                 \
    __builtin_amdgcn_s_setprio(1);                                      \
    _Pragma("unroll") for (int mf_ = 0; mf_ < 8; ++mf_)                 \
      _Pragma("unroll") for (int nf_ = 0; nf_ < 4; ++nf_)               \
        acc[mf_][nf_] = __builtin_amdgcn_mfma_f32_16x16x32_bf16(        \
            av[mf_], bv[nf_], acc[mf_][nf_], 0, 0, 0);                  \
    __builtin_amdgcn_s_setprio(0);                                      \
  } while (0)

  // prologue: tiles 0,1,2 staged; publish 0,1; preload regs from tile 0
  stg(0, 0); stg(1, 1); stg(2, 2);
  asm volatile("s_waitcnt vmcnt(4)" ::: "memory");   // tiles 0,1 landed
  __builtin_amdgcn_s_barrier();                       // ... and visible
  RD(aA, bA, 0);

  for (int jj = 0; jj < NT32; jj += 2) {
    // half 1: pre-read tile jj+1 (published); compute tile jj; stage jj+3
    RD(aB, bB, (jj + 1) & 3);
    MM(aA, bA);
    stg(jj + 3, (jj + 3) & 3);
    asm volatile("s_waitcnt vmcnt(4)" ::: "memory");  // tile jj+2 landed
    __builtin_amdgcn_s_barrier();                      // ... and visible
    // half 2: pre-read tile jj+2; compute tile jj+1; stage jj+4
    RD(aA, bA, (jj + 2) & 3);
    MM(aB, bB);
    stg(jj + 4, (jj + 4) & 3);
    asm volatile("s_waitcnt vmcnt(4)" ::: "memory");
    __builtin_amdgcn_s_barrier();
  }
  asm volatile("s_waitcnt vmcnt(0) lgkmcnt(0)" ::: "memory");
#undef RD
#undef MM

#pragma unroll
  for (int mf = 0; mf < 8; ++mf)
#pragma unroll
    for (int q = 0; q < 4; ++q) {
      int row = t0 + wm * 128 + mf * 16 + (lane >> 4) * 4 + q;
#pragma unroll
      for (int nf = 0; nf < 4; ++nf) {
        int col = o0 + wn * 64 + nf * 16 + l15;
        out[(size_t)row * OUT_DIM + col] = acc[mf][nf][q];
      }
    }
}

extern "C" void kernel_launch(void* const* d_in, const int* in_sizes, int n_in,
                              void* d_out, int out_size, void* d_ws, size_t ws_size,
                              hipStream_t stream) {
  const float* x  = (const float*)d_in[0];
  const float* W  = (const float*)d_in[1];
  const float* rw = (const float*)d_in[2];
  const float* eA = (const float*)d_in[3];
  const float* eB = (const float*)d_in[4];
  float* out = (float*)d_out;
  char* ws = (char*)d_ws;
  if (ws_size < WS_BIG) return;

  u16* Wz = (u16*)(ws + WZ_OFF);
  u16* Az = (u16*)(ws + AZ_OFF);
  u16* Bz = (u16*)(ws + BZ_OFF);
  u16* Cz = (u16*)(ws + CZ_OFF);
  u16* xb = (u16*)(ws + XB_OFF);

  k_prep<<<6144, 256, 0, stream>>>(W, eA, eB, Wz, Az, Bz);
  k_router_lora<<<256, 256, 0, stream>>>(x, rw, Az, xb, Cz);
  k_main32<<<512, 512, 0, stream>>>(xb, Wz, Cz, Bz, out);
}

// Round 12
// 223.378 us; speedup vs baseline: 1.1540x; 1.0093x over previous
//
#include <hip/hip_runtime.h>
#include <stdint.h>

#define D_DIM 2048
#define OUT_DIM 2048
#define NTOK 16384
#define SCALING 1.0f
#define NT32 68   // 64 K-tiles (BK=32) of x@W^T + 4 LoRA-extension tiles

typedef unsigned short u16;
typedef __attribute__((ext_vector_type(8))) short s16x8;
typedef __attribute__((ext_vector_type(4))) float f32x4;

// ws layout (bytes)
#define WZ_OFF  0u           // W bf16 swizzled [2048 o][2048 d]
#define AZ_OFF  8388608u     // experts_A^T bf16 swizzled [128 er][2048 d]
#define BZ_OFF  8912896u     // experts_B^T bf16 swizzled [2048 o][128 er]
#define CZ_OFF  9437184u     // c bf16 swizzled [16384 t][128 er]
#define XB_OFF  14155776u    // x bf16 swizzled [16384][2048]
#define WS_BIG   81264640u

__device__ inline u16 f2bf(float f) {
  union { float f; uint32_t u; } v; v.f = f;
  uint32_t u = v.u;
  u += 0x7FFFu + ((u >> 16) & 1u);   // round-to-nearest-even
  return (u16)(u >> 16);
}

// 32-granule swizzle: within each 32-elem chunk, 8-elem granule s ^= (row>>1)&3
__device__ inline int swz32(int c, int row) {
  return (c & ~31) | (((((c >> 3) & 3) ^ ((row >> 1) & 3))) << 3) | (c & 7);
}

#define GLDS(gp, lp) __builtin_amdgcn_global_load_lds( \
    (const __attribute__((address_space(1))) void*)(gp), \
    (__attribute__((address_space(3))) void*)(lp), 16, 0, 0)

// -------------- tiny prep: experts_A -> A^T bf16 swizzled (needed by router) --
__global__ __launch_bounds__(256) void k_prep_a(const float* __restrict__ A,
                                                u16* __restrict__ Az) {
  int idx = blockIdx.x * 256 + threadIdx.x;    // 8*2048*16
  float v = A[idx];
  int r = idx & 15;
  int d = (idx >> 4) & 2047;
  int e = idx >> 15;
  int er = e * 16 + r;
  Az[(size_t)er * D_DIM + swz32(d, er)] = f2bf(v);
}

// ---- merged router+lora+prep: blocks 0..255 router/lora; rest prep W,B -------
// grid = 256 (router) + 4096 (W: 2048*2048/4 float4 / 256) + 1024 (B: 262144/256)
__global__ __launch_bounds__(256) void k_router_lora(
    const float* __restrict__ x, const float* __restrict__ rw,
    const float* __restrict__ W, const float* __restrict__ Bf,
    const u16* __restrict__ Az, u16* __restrict__ xb, u16* __restrict__ Cz,
    u16* __restrict__ Wz, u16* __restrict__ Bz) {
  int bid = blockIdx.x;
  if (bid >= 256) {
    if (bid < 4352) {                    // W: 2048x2048 f32 -> bf16 swizzled
      int idx = (bid - 256) * 256 + threadIdx.x;
      int o  = idx >> 9;
      int k0 = (idx & 511) * 4;
      const float4 v = *(const float4*)&W[(size_t)o * D_DIM + k0];
      int dst = swz32(k0, o);
      uint32_t p0 = (uint32_t)f2bf(v.x) | ((uint32_t)f2bf(v.y) << 16);
      uint32_t p1 = (uint32_t)f2bf(v.z) | ((uint32_t)f2bf(v.w) << 16);
      *(uint2*)&Wz[(size_t)o * D_DIM + dst] = make_uint2(p0, p1);
    } else {                             // experts_B -> B^T swizzled (1024 blocks)
      int idx = (bid - 4352) * 256 + threadIdx.x;   // 8*16*2048 = 262144
      float v = Bf[idx];
      int er = idx >> 11;
      int o  = idx & 2047;
      Bz[(size_t)o * 128 + swz32(er, o)] = f2bf(v);
    }
    return;
  }
  // ---------------- router + lora (blocks 0..255, 64 tokens each) -------------
  __shared__ u16 Axl[2][64 * 64];     // x chunk bf16 swizzled [64 tok][64 k]
  __shared__ u16 Bzl[2][128 * 64];    // Az chunk [128 er][64 k]
  __shared__ float w8s[64 * 8];
  int tid = threadIdx.x, lane = tid & 63, wid = tid >> 6;
  int t0 = bid * 64;
  const int l15 = lane & 15;
  const int c4 = (tid & 15) * 4;
  const int rbase = tid >> 4;          // 0..15

  f32x4 acc[8];
#pragma unroll
  for (int n = 0; n < 8; ++n) acc[n] = (f32x4){0.f, 0.f, 0.f, 0.f};
  float lgp[4][8];
#pragma unroll
  for (int i = 0; i < 4; ++i)
#pragma unroll
    for (int e = 0; e < 8; ++e) lgp[i][e] = 0.f;

  float4 xn[4];
  // issue x global loads for chunk kc (T14: issue-early)
  auto ldx = [&](int kc) {
    if (kc > 31) kc = 31;
#pragma unroll
    for (int i = 0; i < 4; ++i)
      xn[i] = *(const float4*)&x[(size_t)(t0 + i * 16 + rbase) * D_DIM + kc * 64 + c4];
  };
  // consume chunk kc: fmaf logits (if real), cvt, write xb + Axl[buf], GLDS Az
  auto use = [&](int kc, int buf) {
    bool real = (kc <= 31);
    if (!real) kc = 31;
    if (real) {
#pragma unroll
      for (int e = 0; e < 8; ++e) {
        float4 rv = *(const float4*)&rw[(size_t)e * D_DIM + kc * 64 + c4];
#pragma unroll
        for (int i = 0; i < 4; ++i) {
          lgp[i][e] = fmaf(xn[i].x, rv.x, lgp[i][e]);
          lgp[i][e] = fmaf(xn[i].y, rv.y, lgp[i][e]);
          lgp[i][e] = fmaf(xn[i].z, rv.z, lgp[i][e]);
          lgp[i][e] = fmaf(xn[i].w, rv.w, lgp[i][e]);
        }
      }
    }
#pragma unroll
    for (int i = 0; i < 4; ++i) {
      int row = i * 16 + rbase;
      uint32_t p0 = (uint32_t)f2bf(xn[i].x) | ((uint32_t)f2bf(xn[i].y) << 16);
      uint32_t p1 = (uint32_t)f2bf(xn[i].z) | ((uint32_t)f2bf(xn[i].w) << 16);
      *(uint2*)&xb[(size_t)(t0 + row) * D_DIM + swz32(kc * 64 + c4, row)] =
          make_uint2(p0, p1);
      *(uint2*)&Axl[buf][row * 64 + swz32(c4, row)] = make_uint2(p0, p1);
    }
#pragma unroll
    for (int i = 0; i < 4; ++i) {
      const u16* g = Az + (size_t)(i * 32 + (tid >> 3)) * D_DIM + kc * 64 + (tid & 7) * 8;
      GLDS(g, &Bzl[buf][0] + i * 2048 + tid * 8);
    }
  };

  ldx(0);
  use(0, 0);
  asm volatile("s_waitcnt vmcnt(0) lgkmcnt(0)" ::: "memory");
  __builtin_amdgcn_s_barrier();

  const int g = (lane >> 4) ^ ((l15 >> 1) & 3);
  for (int kc = 0; kc < 32; ++kc) {
    int cur = kc & 1;
    ldx(kc + 1);                        // issue next x loads before MFMA
#pragma unroll
    for (int kk = 0; kk < 2; ++kk) {
      s16x8 af = *(const s16x8*)&Axl[cur][(wid * 16 + l15) * 64 + kk * 32 + g * 8];
#pragma unroll
      for (int nf = 0; nf < 8; ++nf) {
        s16x8 bf = *(const s16x8*)&Bzl[cur][(nf * 16 + l15) * 64 + kk * 32 + g * 8];
        acc[nf] = __builtin_amdgcn_mfma_f32_16x16x32_bf16(af, bf, acc[nf], 0, 0, 0);
      }
    }
    use(kc + 1, cur ^ 1);               // waits x loads, writes next buffers
    asm volatile("s_waitcnt vmcnt(0) lgkmcnt(0)" ::: "memory");
    __builtin_amdgcn_s_barrier();
  }

  // reduce logit partials over the 16-lane c4 groups (exact f32)
#pragma unroll
  for (int i = 0; i < 4; ++i) {
#pragma unroll
    for (int e = 0; e < 8; ++e) {
      float v = lgp[i][e];
      v += __shfl_xor(v, 1, 64);
      v += __shfl_xor(v, 2, 64);
      v += __shfl_xor(v, 4, 64);
      v += __shfl_xor(v, 8, 64);
      lgp[i][e] = v;
    }
    // top-2 (strict >, lowest index wins ties, matching lax.top_k) + softmax
    float l0 = lgp[i][0]; int i0 = 0;
#pragma unroll
    for (int e = 1; e < 8; ++e) if (lgp[i][e] > l0) { l0 = lgp[i][e]; i0 = e; }
    float l1 = -3e38f; int i1 = 0;
#pragma unroll
    for (int e = 0; e < 8; ++e) if (e != i0 && lgp[i][e] > l1) { l1 = lgp[i][e]; i1 = e; }
    float e1 = expf(l1 - l0);
    float inv = 1.f / (1.f + e1);
    if (l15 < 8) {
      int row = i * 16 + rbase;
      w8s[row * 8 + l15] =
          (l15 == i0) ? inv * SCALING : (l15 == i1) ? e1 * inv * SCALING : 0.f;
    }
  }
  __syncthreads();

  // scale + write Cz (expert index == nf since er = nf*16 + l15, l15 < 16)
#pragma unroll
  for (int q = 0; q < 4; ++q) {
    int rl = wid * 16 + (lane >> 4) * 4 + q;
#pragma unroll
    for (int nf = 0; nf < 8; ++nf) {
      float v = acc[nf][q] * w8s[rl * 8 + nf];
      int er = nf * 16 + l15;
      Cz[(size_t)(t0 + rl) * 128 + swz32(er, rl)] = f2bf(v);
    }
  }
}

// ------ 256^2 main GEMM: BK=32, 4-buffer rotation, counted vmcnt (R8-exact) ----
__global__ __launch_bounds__(512, 2) void k_main32(const u16* __restrict__ xb,
                                                   const u16* __restrict__ Wz,
                                                   const u16* __restrict__ Cz,
                                                   const u16* __restrict__ Bz,
                                                   float* __restrict__ out) {
  __shared__ u16 AL[4][8192];   // 4 bufs x [256 rows][32 cols]
  __shared__ u16 BL[4][8192];
  const int tid = threadIdx.x, lane = tid & 63;
  const int wid = tid >> 6, wm = wid >> 2, wn = wid & 3;
  int bid = blockIdx.x;                     // 512 blocks, 512 % 8 == 0
  int swz = (bid & 7) * 64 + (bid >> 3);    // XCD-aware, bijective
  int mt = swz >> 3, nt = swz & 7;
  int t0 = mt * 256, o0 = nt * 256;
  const int l15 = lane & 15;
  const int gA = (lane >> 4) ^ ((l15 >> 1) & 3);
  const int aoff = (wm * 128 + l15) * 32 + gA * 8;   // frag i at +i*512
  const int boff = (wn * 64 + l15) * 32 + gA * 8;
  const int srow = tid >> 2, sc8 = (tid & 3) * 8;

  f32x4 acc[8][4];
#pragma unroll
  for (int m = 0; m < 8; ++m)
#pragma unroll
    for (int n = 0; n < 4; ++n) acc[m][n] = (f32x4){0.f, 0.f, 0.f, 0.f};
  s16x8 aA[8], bA[4], aB[8], bB[4];

  // stage tile t (clamped src) into buffer bufi: 2 A-loads + 2 B-loads
  auto stg = [&](int t, int bufi) {
    if (t > NT32 - 1) t = NT32 - 1;
    const u16 *sa, *sb; int lda, ldb, ca;
    if (t < 64) { sa = xb; lda = D_DIM; sb = Wz; ldb = D_DIM; ca = t * 32; }
    else        { sa = Cz; lda = 128;   sb = Bz; ldb = 128;   ca = (t - 64) * 32; }
#pragma unroll
    for (int i = 0; i < 2; ++i) {
      const u16* g = sa + (size_t)(t0 + i * 128 + srow) * lda + ca + sc8;
      GLDS(g, &AL[bufi][0] + i * 4096 + tid * 8);
    }
#pragma unroll
    for (int i = 0; i < 2; ++i) {
      const u16* g = sb + (size_t)(o0 + i * 128 + srow) * ldb + ca + sc8;
      GLDS(g, &BL[bufi][0] + i * 4096 + tid * 8);
    }
  };

#define RD(av, bv, bufi) do {                                           \
    const u16* ap_ = &AL[bufi][aoff];                                   \
    const u16* bp_ = &BL[bufi][boff];                                   \
    _Pragma("unroll") for (int i_ = 0; i_ < 8; ++i_)                    \
      av[i_] = *(const s16x8*)(ap_ + i_ * 512);                         \
    _Pragma("unroll") for (int j_ = 0; j_ < 4; ++j_)                    \
      bv[j_] = *(const s16x8*)(bp_ + j_ * 512);                         \
  } while (0)

#define MM(av, bv) do {                                                 \
    _Pragma("unroll") for (int mf_ = 0; mf_ < 8; ++mf_)                 \
      _Pragma("unroll") for (int nf_ = 0; nf_ < 4; ++nf_)               \
        acc[mf_][nf_] = __builtin_amdgcn_mfma_f32_16x16x32_bf16(        \
            av[mf_], bv[nf_], acc[mf_][nf_], 0, 0, 0);                  \
  } while (0)

  // prologue: tiles 0,1,2 staged; publish 0,1; preload regs from tile 0
  stg(0, 0); stg(1, 1); stg(2, 2);
  asm volatile("s_waitcnt vmcnt(4)" ::: "memory");   // tiles 0,1 landed
  __builtin_amdgcn_s_barrier();                       // ... and visible
  RD(aA, bA, 0);

  for (int jj = 0; jj < NT32; jj += 2) {
    // half 1: pre-read tile jj+1 (published); compute tile jj; stage jj+3
    RD(aB, bB, (jj + 1) & 3);
    MM(aA, bA);
    stg(jj + 3, (jj + 3) & 3);
    asm volatile("s_waitcnt vmcnt(4)" ::: "memory");  // tile jj+2 landed
    __builtin_amdgcn_s_barrier();                      // ... and visible
    // half 2: pre-read tile jj+2; compute tile jj+1; stage jj+4
    RD(aA, bA, (jj + 2) & 3);
    MM(aB, bB);
    stg(jj + 4, (jj + 4) & 3);
    asm volatile("s_waitcnt vmcnt(4)" ::: "memory");
    __builtin_amdgcn_s_barrier();
  }
  asm volatile("s_waitcnt vmcnt(0) lgkmcnt(0)" ::: "memory");
#undef RD
#undef MM

#pragma unroll
  for (int mf = 0; mf < 8; ++mf)
#pragma unroll
    for (int q = 0; q < 4; ++q) {
      int row = t0 + wm * 128 + mf * 16 + (lane >> 4) * 4 + q;
#pragma unroll
      for (int nf = 0; nf < 4; ++nf) {
        int col = o0 + wn * 64 + nf * 16 + l15;
        out[(size_t)row * OUT_DIM + col] = acc[mf][nf][q];
      }
    }
}

extern "C" void kernel_launch(void* const* d_in, const int* in_sizes, int n_in,
                              void* d_out, int out_size, void* d_ws, size_t ws_size,
                              hipStream_t stream) {
  const float* x  = (const float*)d_in[0];
  const float* W  = (const float*)d_in[1];
  const float* rw = (const float*)d_in[2];
  const float* eA = (const float*)d_in[3];
  const float* eB = (const float*)d_in[4];
  float* out = (float*)d_out;
  char* ws = (char*)d_ws;
  if (ws_size < WS_BIG) return;

  u16* Wz = (u16*)(ws + WZ_OFF);
  u16* Az = (u16*)(ws + AZ_OFF);
  u16* Bz = (u16*)(ws + BZ_OFF);
  u16* Cz = (u16*)(ws + CZ_OFF);
  u16* xb = (u16*)(ws + XB_OFF);

  k_prep_a<<<1024, 256, 0, stream>>>(eA, Az);
  k_router_lora<<<5376, 256, 0, stream>>>(x, rw, W, eB, Az, xb, Cz, Wz, Bz);
  k_main32<<<512, 512, 0, stream>>>(xb, Wz, Cz, Bz, out);
}